// Round 9
// baseline (45.810 us; speedup 1.0000x reference)
//
#include <hip/hip_runtime.h>
#include <hip/hip_bf16.h>
#include <hip/hip_fp16.h>
#include <cfloat>

// Problem constants
#define BB   16
#define LL   4096
#define CC   9
#define DIN  512
#define DOUT 128
#define VV   96

// LDS layout (halves): padded row strides to rotate banks per vocab row
#define PWLD 520    // 512 + 8
#define PELD 136    // 128 + 8

typedef _Float16 h2 __attribute__((ext_vector_type(2)));

#if defined(__has_builtin)
#if __has_builtin(__builtin_amdgcn_fdot2)
#define FDOT2(a, b, c) __builtin_amdgcn_fdot2((a), (b), (c), false)
#endif
#endif
#ifndef FDOT2
__device__ __forceinline__ float FDOT2(h2 a, h2 b, float c) {
    return c + (float)a[0] * (float)b[0] + (float)a[1] * (float)b[1];
}
#endif

__device__ __forceinline__ h2 pack_h2(float lo, float hi) {
    return __builtin_bit_cast(h2, __builtin_amdgcn_cvt_pkrtz(lo, hi));
}

// ---------------------------------------------------------------------------
// Kernel 1: PW[v][k] = sum_o PE[v][o]*W[o][k] -> fp16; y==0 also converts PEh.
// ---------------------------------------------------------------------------
__global__ __launch_bounds__(128)
void pw_kernel(const float* __restrict__ W,    // [DOUT][DIN]
               const float* __restrict__ PE,   // [VV][DOUT]
               __half*      __restrict__ PW,   // [VV][DIN]
               __half*      __restrict__ PEh)  // [VV][DOUT]
{
    const int v = blockIdx.x;                       // 0..95
    const int k = blockIdx.y * 128 + threadIdx.x;   // 0..511
    const float* per = PE + v * DOUT;
    float a = 0.f;
    #pragma unroll 8
    for (int o = 0; o < DOUT; ++o)
        a = fmaf(per[o], W[(size_t)o * DIN + k], a);
    PW[(size_t)v * DIN + k] = __float2half_rn(a);
    if (blockIdx.y == 0)   // DOUT == blockDim.x == 128: one elem per thread
        PEh[(size_t)v * DOUT + threadIdx.x] = __float2half_rn(per[threadIdx.x]);
}

// ---------------------------------------------------------------------------
// Kernel 2: PW + PEh staged in LDS once per CU (grid 256 = 1 block/CU);
// 16 lanes/row, 64 row-slots, 4 row-iterations with 1-deep X/ci prefetch.
// ---------------------------------------------------------------------------
__global__ __launch_bounds__(1024, 4)
void attn_kernel(const float*  __restrict__ X,     // [B*L][DIN]
                 const __half* __restrict__ PW,    // [VV][DIN]
                 const __half* __restrict__ PEh,   // [VV][DOUT]
                 const int*    __restrict__ CIDX,  // [B*L][CC]
                 const int*    __restrict__ CMASK, // [B*L][CC]
                 const int*    __restrict__ SLEN,  // [B]
                 float*        __restrict__ OUT)   // [B*L][DOUT]
{
    __shared__ __half lds_pw[VV * PWLD];   // 99840 B
    __shared__ __half lds_pe[VV * PELD];   // 26112 B

    const int t = threadIdx.x;

    // ---- stage PW: 6144 uint4 chunks, 6 per thread ----
    #pragma unroll
    for (int it = 0; it < 6; ++it) {
        int chunk = t + it * 1024;
        int v = chunk >> 6, kq = chunk & 63;
        uint4 d = *(const uint4*)(PW + (size_t)v * DIN + kq * 8);
        *(uint4*)&lds_pw[v * PWLD + kq * 8] = d;
    }
    // ---- stage PEh: 1536 chunks ----
    {
        if (t < 1536) {
            int v = t >> 4, kq = t & 15;
            *(uint4*)&lds_pe[v * PELD + kq * 8] =
                *(const uint4*)(PEh + (size_t)v * DOUT + kq * 8);
        }
        int c2 = t + 1024;
        if (c2 < 1536) {
            int v2 = c2 >> 4, k2 = c2 & 15;
            *(uint4*)&lds_pe[v2 * PELD + k2 * 8] =
                *(const uint4*)(PEh + (size_t)v2 * DOUT + k2 * 8);
        }
    }
    __syncthreads();

    const int lane = t & 63;
    const int il   = lane & 15;          // lane within row-group
    const int slot = t >> 4;             // 0..63 row-slot in block
    const int rowbase = blockIdx.x * 256;

    // double-buffered prefetch state (all indices compile-time after unroll)
    int    ci[2][CC];
    int    vmw[2][CC];
    float4 xf[2][8];

    // ---- prefetch iteration 0 ----
    {
        const int row = rowbase + slot;
        #pragma unroll
        for (int c = 0; c < CC; ++c) ci[0][c]  = CIDX[(size_t)row * CC + c];
        #pragma unroll
        for (int c = 0; c < CC; ++c) vmw[0][c] = CMASK[(size_t)row * CC + c];
        const float* xr = X + (size_t)row * DIN;
        #pragma unroll
        for (int j = 0; j < 4; ++j) {
            xf[0][j * 2 + 0] = *(const float4*)(xr + il * 8 + 128 * j);
            xf[0][j * 2 + 1] = *(const float4*)(xr + il * 8 + 128 * j + 4);
        }
    }

    #pragma unroll
    for (int i = 0; i < 4; ++i) {
        const int cur = i & 1;
        const int nxt = cur ^ 1;

        // ---- issue next iteration's loads first (hide under compute) ----
        if (i < 3) {
            const int rown = rowbase + (i + 1) * 64 + slot;
            #pragma unroll
            for (int c = 0; c < CC; ++c) ci[nxt][c]  = CIDX[(size_t)rown * CC + c];
            #pragma unroll
            for (int c = 0; c < CC; ++c) vmw[nxt][c] = CMASK[(size_t)rown * CC + c];
            const float* xrn = X + (size_t)rown * DIN;
            #pragma unroll
            for (int j = 0; j < 4; ++j) {
                xf[nxt][j * 2 + 0] = *(const float4*)(xrn + il * 8 + 128 * j);
                xf[nxt][j * 2 + 1] = *(const float4*)(xrn + il * 8 + 128 * j + 4);
            }
        }

        // ---- compute current iteration ----
        const int row = rowbase + i * 64 + slot;
        const int  b     = row >> 12;
        const int  l     = row & (LL - 1);
        const bool inlen = l < SLEN[b];

        h2 xh[16];
        #pragma unroll
        for (int q = 0; q < 8; ++q) {
            xh[q * 2 + 0] = pack_h2(xf[cur][q].x, xf[cur][q].y);
            xh[q * 2 + 1] = pack_h2(xf[cur][q].z, xf[cur][q].w);
        }

        float sc[CC];
        #pragma unroll
        for (int c = 0; c < CC; ++c) sc[c] = 0.f;
        #pragma unroll
        for (int j = 0; j < 4; ++j) {
            #pragma unroll
            for (int c = 0; c < CC; ++c) {
                uint4 pwb = *(const uint4*)&lds_pw[ci[cur][c] * PWLD + j * 128 + il * 8];
                h2 p0 = __builtin_bit_cast(h2, pwb.x);
                h2 p1 = __builtin_bit_cast(h2, pwb.y);
                h2 p2 = __builtin_bit_cast(h2, pwb.z);
                h2 p3 = __builtin_bit_cast(h2, pwb.w);
                float s = sc[c];
                s = FDOT2(xh[j * 4 + 0], p0, s);
                s = FDOT2(xh[j * 4 + 1], p1, s);
                s = FDOT2(xh[j * 4 + 2], p2, s);
                s = FDOT2(xh[j * 4 + 3], p3, s);
                sc[c] = s;
            }
        }
        #pragma unroll
        for (int c = 0; c < CC; ++c) {
            float s = sc[c];
            s += __shfl_xor(s, 1);
            s += __shfl_xor(s, 2);
            s += __shfl_xor(s, 4);
            s += __shfl_xor(s, 8);
            sc[c] = s;
        }

        bool any = false;
        float mx = -FLT_MAX;
        #pragma unroll
        for (int c = 0; c < CC; ++c)
            if (vmw[cur][c]) { mx = fmaxf(mx, sc[c]); any = true; }
        float e[CC];
        float den = 0.f;
        #pragma unroll
        for (int c = 0; c < CC; ++c) {
            e[c] = vmw[cur][c] ? __expf(sc[c] - mx) : 0.f;
            den += e[c];
        }
        const float scale = (any && inlen) ? (1.f / den) : 0.f;

        float o[8];
        #pragma unroll
        for (int j = 0; j < 8; ++j) o[j] = 0.f;
        #pragma unroll
        for (int c = 0; c < CC; ++c) {
            const float w = e[c];
            uint4 peb = *(const uint4*)&lds_pe[ci[cur][c] * PELD + il * 8];
            h2 q0 = __builtin_bit_cast(h2, peb.x);
            h2 q1 = __builtin_bit_cast(h2, peb.y);
            h2 q2 = __builtin_bit_cast(h2, peb.z);
            h2 q3 = __builtin_bit_cast(h2, peb.w);
            o[0] = fmaf(w, (float)q0[0], o[0]); o[1] = fmaf(w, (float)q0[1], o[1]);
            o[2] = fmaf(w, (float)q1[0], o[2]); o[3] = fmaf(w, (float)q1[1], o[3]);
            o[4] = fmaf(w, (float)q2[0], o[4]); o[5] = fmaf(w, (float)q2[1], o[5]);
            o[6] = fmaf(w, (float)q3[0], o[6]); o[7] = fmaf(w, (float)q3[1], o[7]);
        }

        float* op = OUT + (size_t)row * DOUT + il * 8;
        *(float4*)op       = make_float4(o[0] * scale, o[1] * scale, o[2] * scale, o[3] * scale);
        *(float4*)(op + 4) = make_float4(o[4] * scale, o[5] * scale, o[6] * scale, o[7] * scale);
    }
}

extern "C" void kernel_launch(void* const* d_in, const int* in_sizes, int n_in,
                              void* d_out, int out_size, void* d_ws, size_t ws_size,
                              hipStream_t stream) {
    const float* X  = (const float*)d_in[0];
    const float* W  = (const float*)d_in[1];
    const float* PE = (const float*)d_in[2];
    const int*   CI = (const int*)d_in[3];
    const int*   CM = (const int*)d_in[4];
    const int*   SL = (const int*)d_in[5];
    float* OUT = (float*)d_out;
    __half* PW  = (__half*)d_ws;                       // 96*512*2 = 96 KiB
    __half* PEh = (__half*)d_ws + (size_t)VV * DIN;    // +96*128*2 = 24 KiB

    hipLaunchKernelGGL(pw_kernel, dim3(VV, 4), dim3(128), 0, stream, W, PE, PW, PEh);

    const int rows = BB * LL;            // 65536
    hipLaunchKernelGGL(attn_kernel, dim3(rows / 256), dim3(1024), 0, stream,
                       X, PW, PEh, CI, CM, SL, OUT);
}